// Round 12
// baseline (158.302 us; speedup 1.0000x reference)
//
#include <hip/hip_runtime.h>

#define D_MODEL 256
#define LN_EPS 1e-5f
#define NWAVES 1024     // 256 blocks x 4 waves, 1 block/CU
#define NITER  512      // rows per wave; stride between rows = 1024

typedef float f4 __attribute__((ext_vector_type(4)));

// Force a wave-uniform float into an SGPR.
__device__ __forceinline__ float rfl(float x) {
    return __uint_as_float(__builtin_amdgcn_readfirstlane(__float_as_uint(x)));
}

// ---------------------------------------------------------------------------
// R12: EXACT FILL-REPLICA write path. 256 blocks (1/CU, ~12.5% occupancy like
// the 6.75 TB/s fill's 10.7%), grid-stride front (wave w writes rows
// w + 1024*i), PLAIN stores: the dense few-MB moving window is assembled in
// L2 and evicted window-contiguous -> DRAM row locality with few streams.
// Mechanism table: chunked+NT(103)=per-wave streams, saturated; chunked+
// plain(114)=L2 shuffles evictions; stride+NT(121)=no per-stream locality;
// stride+plain+low-occ = the fill's own corner, untested until now.
// Index algebra (no carries, w<1024=2^10): fS = w&511 per-wave const;
// fU = (w>>9) + 2*(i&1); fB = (i>>1)&63. Gram over 5 vars (a0,a1,aU,aB,w2),
// 20 butterfly values. CSI via uniform s_loads, one-body-ahead prefetch.
// ---------------------------------------------------------------------------
__global__ __launch_bounds__(256) void csi_encoder_kernel(
    const float* __restrict__ csi_real,
    const float* __restrict__ csi_imag,
    const float* __restrict__ w_c,
    const float* __restrict__ b_c,
    const float* __restrict__ w_s,
    const float* __restrict__ b_s,
    const float* __restrict__ w_u,
    const float* __restrict__ b_u,
    const float* __restrict__ w_f,
    const float* __restrict__ b_f,
    const float* __restrict__ ln_gamma,
    const float* __restrict__ ln_beta,
    float* __restrict__ out)
{
    const int lane = threadIdx.x & 63;
    const int w0 = __builtin_amdgcn_readfirstlane(blockIdx.x * 4 + (threadIdx.x >> 6));

    const float fS  = (float)(w0 & 511);          // per-wave constant
    const int  bit9 = (w0 >> 9) & 1;
    const float fU0 = (float)bit9;                // rows with i even
    const float fU1 = (float)(bit9 + 2);          // rows with i odd

    // Per-lane (per-d) constants; fold fS into w2.
    const int d0 = lane * 4;
    float a0[4], a1[4], aU[4], aB[4], w2[4], gv[4], bv[4];
#pragma unroll
    for (int j = 0; j < 4; ++j) {
        const int d = d0 + j;
        a0[j] = w_c[d * 2 + 0];
        a1[j] = w_c[d * 2 + 1];
        aU[j] = w_u[d];
        aB[j] = w_s[d];
        const float bsum = b_c[d] + b_s[d] + b_u[d] + b_f[d];
        w2[j] = fmaf(fS, w_f[d], bsum);
        gv[j] = ln_gamma[d];
        bv[j] = ln_beta[d];
    }

    // 20 sums over d: 5x5 Gram (15) + means (5) of h = (a0,a1,aU,aB,w2).
    float p[20];
#pragma unroll
    for (int i = 0; i < 20; ++i) p[i] = 0.0f;
#pragma unroll
    for (int j = 0; j < 4; ++j) {
        p[0]  = fmaf(a0[j], a0[j], p[0]);
        p[1]  = fmaf(a1[j], a1[j], p[1]);
        p[2]  = fmaf(aU[j], aU[j], p[2]);
        p[3]  = fmaf(aB[j], aB[j], p[3]);
        p[4]  = fmaf(w2[j], w2[j], p[4]);
        p[5]  = fmaf(a0[j], a1[j], p[5]);
        p[6]  = fmaf(a0[j], aU[j], p[6]);
        p[7]  = fmaf(a0[j], aB[j], p[7]);
        p[8]  = fmaf(a0[j], w2[j], p[8]);
        p[9]  = fmaf(a1[j], aU[j], p[9]);
        p[10] = fmaf(a1[j], aB[j], p[10]);
        p[11] = fmaf(a1[j], w2[j], p[11]);
        p[12] = fmaf(aU[j], aB[j], p[12]);
        p[13] = fmaf(aU[j], w2[j], p[13]);
        p[14] = fmaf(aB[j], w2[j], p[14]);
        p[15] += a0[j];
        p[16] += a1[j];
        p[17] += aU[j];
        p[18] += aB[j];
        p[19] += w2[j];
    }
#pragma unroll
    for (int off = 32; off >= 1; off >>= 1) {
#pragma unroll
        for (int i = 0; i < 20; ++i) p[i] += __shfl_xor(p[i], off, 64);
    }

    const float inv = 1.0f / 256.0f;
    const float E00 = rfl(p[0] * inv);
    const float E11 = rfl(p[1] * inv);
    const float EUU = rfl(p[2] * inv);
    const float EBB = rfl(p[3] * inv);
    const float Eww = rfl(p[4] * inv);
    const float F01 = rfl(2.0f * p[5]  * inv);
    const float F0U = rfl(2.0f * p[6]  * inv);
    const float F0B = rfl(2.0f * p[7]  * inv);
    const float F0w = rfl(2.0f * p[8]  * inv);
    const float F1U = rfl(2.0f * p[9]  * inv);
    const float F1B = rfl(2.0f * p[10] * inv);
    const float F1w = rfl(2.0f * p[11] * inv);
    const float FUB = rfl(2.0f * p[12] * inv);
    const float FUw = rfl(2.0f * p[13] * inv);
    const float FBw = rfl(2.0f * p[14] * inv);
    const float M0  = rfl(p[15] * inv);
    const float M1  = rfl(p[16] * inv);
    const float MU  = rfl(p[17] * inv);
    const float MB  = rfl(p[18] * inv);
    const float Mw  = rfl(p[19] * inv);

    // Uniform bases; per-i strides: CSI 1024 floats (4 KB), out 1024 rows (1 MB).
    const float* __restrict__ cr = csi_real + w0;
    const float* __restrict__ ci = csi_imag + w0;
    float* __restrict__ op = out + (size_t)w0 * D_MODEL + d0;

    // Process one body = 4 rows (i = 4b..4b+3).
    auto process = [&](int b, const float* re4, const float* im4) {
        const float fBa = (float)((2 * b) & 63);
        const float fBb = (float)((2 * b + 1) & 63);
#pragma unroll
        for (int k = 0; k < 4; ++k) {
            const float re = re4[k];
            const float im = im4[k];
            const float fU = (k & 1) ? fU1 : fU0;
            const float fB = (k >> 1) ? fBb : fBa;

            const float mu = fmaf(M0, re, fmaf(M1, im,
                             fmaf(MU, fU, fmaf(MB, fB, Mw))));
            const float ms = fmaf(re, fmaf(E00, re, fmaf(F01, im, fmaf(F0U, fU, fmaf(F0B, fB, F0w)))),
                             fmaf(im, fmaf(E11, im, fmaf(F1U, fU, fmaf(F1B, fB, F1w))),
                             fmaf(fU, fmaf(EUU, fU, fmaf(FUB, fB, FUw)),
                             fmaf(fB, fmaf(EBB, fB, FBw), Eww))));
            const float var  = fmaf(-mu, mu, ms);
            const float rstd = rsqrtf(var + LN_EPS);

            f4 o;
#pragma unroll
            for (int kk = 0; kk < 4; ++kk) {
                const float t = fmaf(re, a0[kk], fmaf(im, a1[kk],
                                fmaf(fU, aU[kk], fmaf(fB, aB[kk], w2[kk]))));
                o[kk] = fmaf((t - mu) * rstd, gv[kk], bv[kk]);
            }
            *reinterpret_cast<f4*>(op + ((size_t)(4 * b + k) << 18)) = o; // plain store
        }
    };

    // One-body-ahead scalar prefetch (uniform addresses -> s_loads).
    float cre[4], cim[4];
#pragma unroll
    for (int k = 0; k < 4; ++k) {
        cre[k] = cr[(size_t)k << 10];
        cim[k] = ci[(size_t)k << 10];
    }
    for (int b = 0; b < 127; ++b) {
        float nre[4], nim[4];
#pragma unroll
        for (int k = 0; k < 4; ++k) {
            nre[k] = cr[(size_t)(4 * b + 4 + k) << 10];
            nim[k] = ci[(size_t)(4 * b + 4 + k) << 10];
        }
        process(b, cre, cim);
#pragma unroll
        for (int k = 0; k < 4; ++k) { cre[k] = nre[k]; cim[k] = nim[k]; }
    }
    process(127, cre, cim);
}

extern "C" void kernel_launch(void* const* d_in, const int* in_sizes, int n_in,
                              void* d_out, int out_size, void* d_ws, size_t ws_size,
                              hipStream_t stream) {
    const float* csi_real = (const float*)d_in[0];
    const float* csi_imag = (const float*)d_in[1];
    const float* w_c      = (const float*)d_in[2];
    const float* b_c      = (const float*)d_in[3];
    const float* w_s      = (const float*)d_in[4];
    const float* b_s      = (const float*)d_in[5];
    const float* w_u      = (const float*)d_in[6];
    const float* b_u      = (const float*)d_in[7];
    const float* w_f      = (const float*)d_in[8];
    const float* b_f      = (const float*)d_in[9];
    const float* ln_gamma = (const float*)d_in[10];
    const float* ln_beta  = (const float*)d_in[11];
    float* out = (float*)d_out;

    // 256 blocks x 4 waves = 1024 waves; grid-stride, 512 rows each.
    csi_encoder_kernel<<<256, 256, 0, stream>>>(
        csi_real, csi_imag, w_c, b_c, w_s, b_s, w_u, b_u, w_f, b_f,
        ln_gamma, ln_beta, out);
}

// Round 13
// 105.211 us; speedup vs baseline: 1.5046x; 1.5046x over previous
//
#include <hip/hip_runtime.h>

#define D_MODEL 256
#define LN_EPS 1e-5f

typedef float f4 __attribute__((ext_vector_type(4)));

// Force a wave-uniform float into an SGPR.
__device__ __forceinline__ float rfl(float x) {
    return __uint_as_float(__builtin_amdgcn_readfirstlane(__float_as_uint(x)));
}
// Broadcast lane j's value of v (wave-uniform j) — VALU op, no memory counter.
__device__ __forceinline__ float rdlane(float v, int j) {
    return __uint_as_float(__builtin_amdgcn_readlane(__float_as_uint(v), j));
}

// ---------------------------------------------------------------------------
// R13 = R11 structure (8192 waves x 64-row contiguous chunks, readlane CSI,
// SGPR Gram constants, closed-form LayerNorm) with TWO deltas forming a
// single-lever A/B against R7 (chunked+plain, no swizzle, 114 us):
//   1. PLAIN stores (L2 write-allocate, like the 6.75 TB/s fill kernels)
//   2. bijective XCD swizzle: block bid runs on XCD bid&7 (round-robin
//      dispatch), and is assigned chunk (bid&7)*256 + bid>>3, so each XCD's
//      private L2 writes a CONTIGUOUS 64-MB output span. Dirty evictions
//      then leave L2 in near-sequential order -> DRAM row locality, the
//      mechanism hypothesized to be the fill kernels' actual advantage.
// If this lands >= 103 us, the pattern space is exhausted and R11 (102.7 us)
// is the declared roofline config.
// ---------------------------------------------------------------------------
__global__ __launch_bounds__(256, 8) void csi_encoder_kernel(
    const float* __restrict__ csi_real,
    const float* __restrict__ csi_imag,
    const float* __restrict__ w_c,
    const float* __restrict__ b_c,
    const float* __restrict__ w_s,
    const float* __restrict__ b_s,
    const float* __restrict__ w_u,
    const float* __restrict__ b_u,
    const float* __restrict__ w_f,
    const float* __restrict__ b_f,
    const float* __restrict__ ln_gamma,
    const float* __restrict__ ln_beta,
    float* __restrict__ out)
{
    const int lane = threadIdx.x & 63;
    // XCD-swizzle: XCD (bid&7) gets contiguous chunk range [ (bid&7)*256, +256 ).
    const int bid  = blockIdx.x;
    const int sbid = (bid & 7) * 256 + (bid >> 3);            // bijective, 2048%8==0
    const int waveId = sbid * 4 + (threadIdx.x >> 6);         // 0..8191
    const int rbase = __builtin_amdgcn_readfirstlane(waveId * 64);

    // Prologue CSI loads: lane l holds row (rbase+l); latency hides under the
    // coefficient loads + Gram butterfly below.
    const float re_v = csi_real[rbase + lane];
    const float im_v = csi_imag[rbase + lane];

    const int s0i = rbase & 511;                 // starting subcarrier index
    const float fU = (float)((rbase >> 9) & 3);
    const float fB = (float)((rbase >> 11) & 63);

    // Per-lane (per-d) constants for d = d0..d0+3.
    const int d0 = lane * 4;
    float a0[4], a1[4], a2[4], wv[4], gv[4], bv[4];
#pragma unroll
    for (int j = 0; j < 4; ++j) {
        const int d = d0 + j;
        a0[j] = w_c[d * 2 + 0];
        a1[j] = w_c[d * 2 + 1];
        a2[j] = w_f[d];
        const float bsum = b_c[d] + b_s[d] + b_u[d] + b_f[d];
        wv[j] = fmaf(fB, w_s[d], fmaf(fU, w_u[d], bsum));
        gv[j] = ln_gamma[d];
        bv[j] = ln_beta[d];
    }

    // 14 sums over d: 4x4 Gram (10) + means (4) of h = (a0, a1, a2, w).
    float p[14];
#pragma unroll
    for (int i = 0; i < 14; ++i) p[i] = 0.0f;
#pragma unroll
    for (int j = 0; j < 4; ++j) {
        p[0]  = fmaf(a0[j], a0[j], p[0]);
        p[1]  = fmaf(a1[j], a1[j], p[1]);
        p[2]  = fmaf(a2[j], a2[j], p[2]);
        p[3]  = fmaf(wv[j], wv[j], p[3]);
        p[4]  = fmaf(a0[j], a1[j], p[4]);
        p[5]  = fmaf(a0[j], a2[j], p[5]);
        p[6]  = fmaf(a0[j], wv[j], p[6]);
        p[7]  = fmaf(a1[j], a2[j], p[7]);
        p[8]  = fmaf(a1[j], wv[j], p[8]);
        p[9]  = fmaf(a2[j], wv[j], p[9]);
        p[10] += a0[j];
        p[11] += a1[j];
        p[12] += a2[j];
        p[13] += wv[j];
    }
#pragma unroll
    for (int off = 32; off >= 1; off >>= 1) {
#pragma unroll
        for (int i = 0; i < 14; ++i) p[i] += __shfl_xor(p[i], off, 64);
    }

    // Wave-uniform Gram constants -> SGPRs.
    const float inv = 1.0f / 256.0f;
    const float E00 = rfl(p[0] * inv);
    const float E11 = rfl(p[1] * inv);
    const float E22 = rfl(p[2] * inv);
    const float E33 = rfl(p[3] * inv);
    const float F01 = rfl(2.0f * p[4] * inv);
    const float F02 = rfl(2.0f * p[5] * inv);
    const float F03 = rfl(2.0f * p[6] * inv);
    const float F12 = rfl(2.0f * p[7] * inv);
    const float F13 = rfl(2.0f * p[8] * inv);
    const float F23 = rfl(2.0f * p[9] * inv);
    const float M0  = rfl(p[10] * inv);
    const float M1  = rfl(p[11] * inv);
    const float M2  = rfl(p[12] * inv);
    const float M3  = rfl(p[13] * inv);

    float* __restrict__ op = out + (size_t)rbase * D_MODEL + d0;

#pragma unroll 4
    for (int j = 0; j < 64; ++j) {
        const float re = rdlane(re_v, j);    // v_readlane: no memory counter
        const float im = rdlane(im_v, j);
        const float fS = (float)(s0i + j);

        const float mu = fmaf(M0, re, fmaf(M1, im, fmaf(M2, fS, M3)));
        const float ms = fmaf(re, fmaf(E00, re, fmaf(F01, im, fmaf(F02, fS, F03))),
                         fmaf(im, fmaf(E11, im, fmaf(F12, fS, F13)),
                         fmaf(fS, fmaf(E22, fS, F23), E33)));
        const float var  = fmaf(-mu, mu, ms);
        const float rstd = rsqrtf(var + LN_EPS);

        f4 o;
#pragma unroll
        for (int k = 0; k < 4; ++k) {
            const float t = fmaf(re, a0[k], fmaf(im, a1[k], fmaf(fS, a2[k], wv[k])));
            o[k] = fmaf((t - mu) * rstd, gv[k], bv[k]);
        }
        *reinterpret_cast<f4*>(op + (size_t)j * D_MODEL) = o;   // PLAIN store (through L2)
    }
}

extern "C" void kernel_launch(void* const* d_in, const int* in_sizes, int n_in,
                              void* d_out, int out_size, void* d_ws, size_t ws_size,
                              hipStream_t stream) {
    const float* csi_real = (const float*)d_in[0];
    const float* csi_imag = (const float*)d_in[1];
    const float* w_c      = (const float*)d_in[2];
    const float* b_c      = (const float*)d_in[3];
    const float* w_s      = (const float*)d_in[4];
    const float* b_s      = (const float*)d_in[5];
    const float* w_u      = (const float*)d_in[6];
    const float* b_u      = (const float*)d_in[7];
    const float* w_f      = (const float*)d_in[8];
    const float* b_f      = (const float*)d_in[9];
    const float* ln_gamma = (const float*)d_in[10];
    const float* ln_beta  = (const float*)d_in[11];
    float* out = (float*)d_out;

    // 2048 blocks x 4 waves = 8192 waves; each owns a contiguous 64-row chunk.
    // Chunk assignment is XCD-swizzled inside the kernel.
    csi_encoder_kernel<<<2048, 256, 0, stream>>>(
        csi_real, csi_imag, w_c, b_c, w_s, b_s, w_u, b_u, w_f, b_f,
        ln_gamma, ln_beta, out);
}